// Round 16
// baseline (94.673 us; speedup 1.0000x reference)
//
#include <hip/hip_runtime.h>

typedef short v8s __attribute__((ext_vector_type(8)));
typedef float v4f __attribute__((ext_vector_type(4)));

#define AS1 __attribute__((address_space(1)))
#define AS3 __attribute__((address_space(3)))

__device__ __forceinline__ ushort f2bf(float f) {
  union { float f; unsigned u; } v; v.f = f;
  unsigned u = v.u;
  unsigned r = (u + 0x7FFFu + ((u >> 16) & 1u)) >> 16;
  return (ushort)r;
}

// hardware 2^x, single v_exp_f32
__device__ __forceinline__ float exp2_hw(float x) {
  float r;
  asm("v_exp_f32 %0, %1" : "=v"(r) : "v"(x));
  return r;
}

// pack 2 f32 -> 2 bf16 in one u32 (lo = a, hi = b)
__device__ __forceinline__ unsigned cvtpk_bf16(float a, float b) {
  unsigned r;
  asm("v_cvt_pk_bf16_f32 %0, %1, %2" : "=v"(r) : "v"(a), "v"(b));
  return r;
}

// ---------------- fused cast fp32 -> bf16 ----------------
__global__ void cast3_kernel(const float* __restrict__ a, int na4,
                             const float* __restrict__ b, int nb4,
                             const float* __restrict__ c, int nc4,
                             ushort* __restrict__ da, ushort* __restrict__ db,
                             ushort* __restrict__ dc) {
  int i = blockIdx.x * blockDim.x + threadIdx.x;
  const float* s; ushort* d; int off;
  if (i < na4) { s = a; d = da; off = i; }
  else if (i < na4 + nb4) { s = b; d = db; off = i - na4; }
  else if (i < na4 + nb4 + nc4) { s = c; d = dc; off = i - na4 - nb4; }
  else return;
  float4 f = ((const float4*)s)[off];
  ushort4 o;
  o.x = f2bf(f.x); o.y = f2bf(f.y); o.z = f2bf(f.z); o.w = f2bf(f.w);
  ((ushort4*)d)[off] = o;
}

// ---------------- GEMM v2: single-buffer, swizzled, stage-under-MFMA -------
// (r8-proven; Q epilogue scale 0.125*log2e; V written in PERMUTED-s layout
// matching attn's lane-local P fragments.)
template<int MODE, int BM, int BN>
__global__ __launch_bounds__(256, (BM == 64) ? 4 : 3)
void gemm_bt(const ushort* __restrict__ A, const ushort* __restrict__ B,
             ushort* __restrict__ q, ushort* __restrict__ k, ushort* __restrict__ vtp,
             float* __restrict__ outF, int M, int N, int K)
{
  constexpr int WN = BN / 64;
  constexpr int MI = (WN == 2) ? (BM / 32) : (BM / 64);
  constexpr int NI = 4;
  __shared__ ushort lA[BM * 64];
  __shared__ ushort lB[BN * 64];
  const int tid = threadIdx.x;
  const int w = tid >> 6, lane = tid & 63;
  const int m0 = blockIdx.x * BM, n0 = blockIdx.y * BN;
  const int g = lane >> 4, lr = lane & 15;
  const int wm = (WN == 2) ? (w >> 1) : w;
  const int wn = (WN == 2) ? (w & 1) : 0;

  const int r8 = lane >> 3;
  const int swz8 = ((lane & 7) ^ r8) * 8;
  const ushort* ga = A + (size_t)(m0 + w * 8 + r8) * K + swz8;
  const ushort* gb = B + (size_t)(n0 + w * 8 + r8) * K + swz8;
  const int xr = (lr & 7) << 3;

  v4f acc[MI][NI];
  const v4f zf = {0.0f, 0.0f, 0.0f, 0.0f};
#pragma unroll
  for (int mi = 0; mi < MI; mi++)
#pragma unroll
    for (int ni = 0; ni < NI; ni++) acc[mi][ni] = zf;

  auto stage = [&](int k0) {
#pragma unroll
    for (int i = 0; i < BM / 32; i++)
      __builtin_amdgcn_global_load_lds((const AS1 void*)(ga + (size_t)(i * 32) * K + k0),
                                       (AS3 void*)(&lA[(i * 32 + w * 8) * 64]), 16, 0, 0);
#pragma unroll
    for (int i = 0; i < BN / 32; i++)
      __builtin_amdgcn_global_load_lds((const AS1 void*)(gb + (size_t)(i * 32) * K + k0),
                                       (AS3 void*)(&lB[(i * 32 + w * 8) * 64]), 16, 0, 0);
  };

  stage(0);
  asm volatile("s_waitcnt vmcnt(0)" ::: "memory");
  asm volatile("s_barrier" ::: "memory");

  const int NTk = K >> 6;
  for (int t = 0; t < NTk; t++) {
    v8s af[MI][2], bf[NI][2];
#pragma unroll
    for (int mi = 0; mi < MI; mi++)
#pragma unroll
      for (int kc = 0; kc < 2; kc++)
        af[mi][kc] = *(const v8s*)(&lA[(wm * (MI * 16) + mi * 16 + lr) * 64 + ((kc * 32 + g * 8) ^ xr)]);
#pragma unroll
    for (int ni = 0; ni < NI; ni++)
#pragma unroll
      for (int kc = 0; kc < 2; kc++)
        bf[ni][kc] = *(const v8s*)(&lB[(wn * 64 + ni * 16 + lr) * 64 + ((kc * 32 + g * 8) ^ xr)]);
    asm volatile("s_waitcnt lgkmcnt(0)" ::: "memory");
    asm volatile("s_barrier" ::: "memory");
    if (t + 1 < NTk) stage((t + 1) * 64);
    __builtin_amdgcn_sched_barrier(0);
    __builtin_amdgcn_s_setprio(1);
#pragma unroll
    for (int kc = 0; kc < 2; kc++)
#pragma unroll
      for (int mi = 0; mi < MI; mi++)
#pragma unroll
        for (int ni = 0; ni < NI; ni++)
          acc[mi][ni] = __builtin_amdgcn_mfma_f32_16x16x32_bf16(af[mi][kc], bf[ni][kc], acc[mi][ni], 0, 0, 0);
    __builtin_amdgcn_s_setprio(0);
    asm volatile("s_waitcnt vmcnt(0)" ::: "memory");
    asm volatile("s_barrier" ::: "memory");
  }

#pragma unroll
  for (int mi = 0; mi < MI; mi++) {
#pragma unroll
    for (int ni = 0; ni < NI; ni++) {
      v4f c = acc[mi][ni];
      const int row0 = m0 + wm * (MI * 16) + mi * 16 + g * 4;
      const int col = n0 + wn * 64 + ni * 16 + lr;
      if (MODE == 0) {
        const int b = row0 >> 11, s0r = row0 & 2047;
        const int part = col >> 10, c2 = col & 1023;
        const int h = c2 >> 6, d = c2 & 63;
        if (part == 2) {
          // permuted-s position: p = (s&~31) | ((s>>2)&3)<<3 | ((s>>4)&1)<<2
          const int sp = (s0r & ~31) | (((s0r >> 2) & 3) << 3) | (((s0r >> 4) & 1) << 2);
          ushort4 pk4;
          pk4.x = f2bf(c[0]); pk4.y = f2bf(c[1]); pk4.z = f2bf(c[2]); pk4.w = f2bf(c[3]);
          *(ushort4*)(vtp + ((size_t)(b * 16 + h) * 64 + d) * 2048 + sp) = pk4;
        } else {
          const size_t idx = ((size_t)(b * 16 + h) * 2048 + s0r) * 64 + d;
#pragma unroll
          for (int r = 0; r < 4; r++) {
            const float val = c[r];
            if (part == 0) q[idx + (size_t)r * 64] = f2bf(val * 0.18033688f);
            else           k[idx + (size_t)r * 64] = f2bf(val);
          }
        }
      } else {
#pragma unroll
        for (int r = 0; r < 4; r++)
          outF[(size_t)(row0 + r) * N + col] = c[r];
      }
    }
  }
}

// ---------------- flash attention v10: 32 q-rows/wave, P in registers ------
// v9's swapped-QK^T/lane-local-P machinery, doubled: each wave owns two
// 16-row q-sub-blocks; K/V frags (sub-block independent!) read from LDS ONCE
// per tile and reused -> LDS-read traffic per unit work halves (attn was
// LDS-traffic-bound). Block = 128 q-rows, grid (32 bh, 16 slots) = 2/CU;
// slot map chunk = slot<8 ? 15-slot : slot-8 -> resident pairs = 34 tiles/CU.
__global__ __launch_bounds__(256, 2)
void attn_kernel(const ushort* __restrict__ qh, const ushort* __restrict__ kh,
                 const ushort* __restrict__ vt, ushort* __restrict__ ao)
{
  __shared__ ushort lK0[64 * 64], lK1[64 * 64];
  __shared__ ushort lV0[64 * 64], lV1[64 * 64];

  const int bh = blockIdx.x;
  const int slot = blockIdx.y;
  const int chunk = (slot < 8) ? (15 - slot) : (slot - 8);
  const int q0 = chunk * 128;
  const int NT = 2 * chunk + 2;

  const int w = threadIdx.x >> 6;
  const int lane = threadIdx.x & 63;
  const int g = lane >> 4, lr = lane & 15;
  const int lsub = lane >> 3;
  const int swz8 = ((lane & 7) ^ lsub) * 8;
  const int wrow = q0 + w * 32;
  const int qq0 = wrow + lr;                // lane's q-row, sub-block 0
  const int qq1 = wrow + 16 + lr;           // sub-block 1

  const ushort* Qp = qh + (size_t)bh * 2048 * 64;
  const ushort* Kp = kh + (size_t)bh * 2048 * 64;
  const ushort* Vp = vt + (size_t)bh * 64 * 2048;

  v8s aq0[2], aq1[2];
#pragma unroll
  for (int kc = 0; kc < 2; kc++) {
    aq0[kc] = *(const v8s*)(Qp + (size_t)(wrow + lr) * 64 + kc * 32 + g * 8);
    aq1[kc] = *(const v8s*)(Qp + (size_t)(wrow + 16 + lr) * 64 + kc * 32 + g * 8);
  }

  v4f o0[4], o1[4];
  float lp0 = 0.0f, lp1 = 0.0f;             // per-lane partial l
  const v4f zf = {0.0f, 0.0f, 0.0f, 0.0f};
#pragma unroll
  for (int ni = 0; ni < 4; ni++) { o0[ni] = zf; o1[ni] = zf; }

  auto stage = [&](ushort* dK, ushort* dV, int kv0) {
#pragma unroll
    for (int i = 0; i < 2; i++) {
      __builtin_amdgcn_global_load_lds(
          (const AS1 void*)(Kp + (size_t)(kv0 + i * 32 + w * 8 + lsub) * 64 + swz8),
          (AS3 void*)(dK + (i * 32 + w * 8) * 64), 16, 0, 0);
      __builtin_amdgcn_global_load_lds(
          (const AS1 void*)(Vp + (size_t)(i * 32 + w * 8 + lsub) * 2048 + kv0 + swz8),
          (AS3 void*)(dV + (i * 32 + w * 8) * 64), 16, 0, 0);
    }
  };

  auto rdfrag = [&](const ushort* base, int ni, int kc) -> v8s {
    const int row = ni * 16 + lr;
    const int off = (((kc * 64 + g * 16) ^ ((lr & 7) << 4)) >> 1);
    return *(const v8s*)(base + row * 64 + off);
  };

  // softmax (exp+pack, lane-local) for one sub-block's S -> pk[8]
  auto softpk = [&](v4f (&s)[4], int qq, int kv0, bool diag, float& lp, unsigned (&pk)[8]) {
    if (diag) {
#pragma unroll
      for (int ni = 0; ni < 4; ni++)
#pragma unroll
        for (int r = 0; r < 4; r++) {
          const int kk = kv0 + ni * 16 + g * 4 + r;
          if (kk > qq) s[ni][r] = -1.0e30f;
        }
    }
#pragma unroll
    for (int ni = 0; ni < 4; ni++) {
      const float p0 = exp2_hw(s[ni][0]);
      const float p1 = exp2_hw(s[ni][1]);
      const float p2 = exp2_hw(s[ni][2]);
      const float p3 = exp2_hw(s[ni][3]);
      lp += (p0 + p1) + (p2 + p3);
      pk[2 * ni]     = cvtpk_bf16(p0, p1);
      pk[2 * ni + 1] = cvtpk_bf16(p2, p3);
    }
  };

  auto compute = [&](const ushort* bK, const ushort* bV, int kv0) {
    if (kv0 > wrow + 31) return;            // wave-uniform: tail tiles
    const bool act0 = (kv0 <= wrow + 15);   // sub-block 0 still active
    v8s kf[2][4];
#pragma unroll
    for (int kc = 0; kc < 2; kc++)
#pragma unroll
      for (int ni = 0; ni < 4; ni++) kf[kc][ni] = rdfrag(bK, ni, kc);

    v4f s0[4], s1[4];
#pragma unroll
    for (int ni = 0; ni < 4; ni++) { s0[ni] = zf; s1[ni] = zf; }
    __builtin_amdgcn_s_setprio(1);
#pragma unroll
    for (int kc = 0; kc < 2; kc++)
#pragma unroll
      for (int ni = 0; ni < 4; ni++) {
        if (act0)
          s0[ni] = __builtin_amdgcn_mfma_f32_16x16x32_bf16(kf[kc][ni], aq0[kc], s0[ni], 0, 0, 0);
        s1[ni] = __builtin_amdgcn_mfma_f32_16x16x32_bf16(kf[kc][ni], aq1[kc], s1[ni], 0, 0, 0);
      }
    __builtin_amdgcn_s_setprio(0);

    unsigned pk0[8], pk1[8];
    if (act0) softpk(s0, qq0, kv0, kv0 + 63 > wrow, lp0, pk0);
    softpk(s1, qq1, kv0, kv0 + 63 > wrow + 16, lp1, pk1);

    v8s vf[2][4];
#pragma unroll
    for (int kc = 0; kc < 2; kc++)
#pragma unroll
      for (int d = 0; d < 4; d++) vf[kc][d] = rdfrag(bV, d, kc);

    __builtin_amdgcn_s_setprio(1);
#pragma unroll
    for (int kc = 0; kc < 2; kc++) {
      union { v8s v; unsigned u[4]; } ap0, ap1;
#pragma unroll
      for (int j = 0; j < 4; j++) { ap0.u[j] = pk0[4 * kc + j]; ap1.u[j] = pk1[4 * kc + j]; }
#pragma unroll
      for (int d = 0; d < 4; d++) {
        if (act0)
          o0[d] = __builtin_amdgcn_mfma_f32_16x16x32_bf16(ap0.v, vf[kc][d], o0[d], 0, 0, 0);
        o1[d] = __builtin_amdgcn_mfma_f32_16x16x32_bf16(ap1.v, vf[kc][d], o1[d], 0, 0, 0);
      }
    }
    __builtin_amdgcn_s_setprio(0);
  };

  stage(lK0, lV0, 0);
  asm volatile("s_waitcnt vmcnt(0)" ::: "memory");
  __builtin_amdgcn_s_barrier();

  for (int t = 0; t < NT; t++) {
    const int kv0 = t * 64;
    if ((t & 1) == 0) {
      if (t + 1 < NT) stage(lK1, lV1, kv0 + 64);
      compute(lK0, lV0, kv0);
    } else {
      if (t + 1 < NT) stage(lK0, lV0, kv0 + 64);
      compute(lK1, lV1, kv0);
    }
    asm volatile("s_waitcnt vmcnt(0)" ::: "memory");
    __builtin_amdgcn_s_barrier();
  }

  // finalize l: reduce per-lane partials across the 4 g-groups
  lp0 += __shfl_xor(lp0, 16);
  lp0 += __shfl_xor(lp0, 32);
  lp1 += __shfl_xor(lp1, 16);
  lp1 += __shfl_xor(lp1, 32);
  float rl0[4], rl1[4];
#pragma unroll
  for (int r = 0; r < 4; r++) {
    rl0[r] = 1.0f / __shfl(lp0, g * 4 + r);
    rl1[r] = 1.0f / __shfl(lp1, g * 4 + r);
  }

  const int b = bh >> 4, h = bh & 15;
#pragma unroll
  for (int ni = 0; ni < 4; ni++) {
#pragma unroll
    for (int r = 0; r < 4; r++) {
      const int srow0 = wrow + g * 4 + r;
      ao[((size_t)(b * 2048 + srow0)) * 1024 + h * 64 + ni * 16 + lr] = f2bf(o0[ni][r] * rl0[r]);
      const int srow1 = wrow + 16 + g * 4 + r;
      ao[((size_t)(b * 2048 + srow1)) * 1024 + h * 64 + ni * 16 + lr] = f2bf(o1[ni][r] * rl1[r]);
    }
  }
}

extern "C" void kernel_launch(void* const* d_in, const int* in_sizes, int n_in,
                              void* d_out, int out_size, void* d_ws, size_t ws_size,
                              hipStream_t stream)
{
  const float* x     = (const float*)d_in[0];
  // d_in[1] = attention_mask (causal by construction; unused)
  const float* w_qkv = (const float*)d_in[2];
  const float* w_out = (const float*)d_in[3];
  float* out = (float*)d_out;

  char* ws = (char*)d_ws;
  ushort* xb  = (ushort*)(ws);                              // 8 MB (reused as ao)
  ushort* wqb = (ushort*)(ws + (size_t)8  * 1024 * 1024);   // 6 MB
  ushort* wob = (ushort*)(ws + (size_t)14 * 1024 * 1024);   // 2 MB
  ushort* qh  = (ushort*)(ws + (size_t)16 * 1024 * 1024);   // 8 MB
  ushort* kh  = (ushort*)(ws + (size_t)24 * 1024 * 1024);   // 8 MB
  ushort* vt  = (ushort*)(ws + (size_t)32 * 1024 * 1024);   // 8 MB
  ushort* ao  = xb;  // xb dead after gemm_qkv

  cast3_kernel<<<8192, 256, 0, stream>>>(x, 1048576, w_qkv, 786432, w_out, 262144,
                                         xb, wqb, wob);
  gemm_bt<0, 128, 128><<<dim3(32, 24), 256, 0, stream>>>(xb, wqb, qh, kh, vt, nullptr, 4096, 3072, 1024);
  attn_kernel<<<dim3(32, 16), 256, 0, stream>>>(qh, kh, vt, ao);
  gemm_bt<1, 64, 64><<<dim3(64, 16), 256, 0, stream>>>(ao, wob, nullptr, nullptr, nullptr, out, 4096, 1024, 1024);
}

// Round 17
// 87.177 us; speedup vs baseline: 1.0860x; 1.0860x over previous
//
#include <hip/hip_runtime.h>

typedef short v8s __attribute__((ext_vector_type(8)));
typedef float v4f __attribute__((ext_vector_type(4)));

#define AS1 __attribute__((address_space(1)))
#define AS3 __attribute__((address_space(3)))

__device__ __forceinline__ ushort f2bf(float f) {
  union { float f; unsigned u; } v; v.f = f;
  unsigned u = v.u;
  unsigned r = (u + 0x7FFFu + ((u >> 16) & 1u)) >> 16;
  return (ushort)r;
}

// hardware 2^x, single v_exp_f32
__device__ __forceinline__ float exp2_hw(float x) {
  float r;
  asm("v_exp_f32 %0, %1" : "=v"(r) : "v"(x));
  return r;
}

// pack 2 f32 -> 2 bf16 in one u32 (lo = a, hi = b)
__device__ __forceinline__ unsigned cvtpk_bf16(float a, float b) {
  unsigned r;
  asm("v_cvt_pk_bf16_f32 %0, %1, %2" : "=v"(r) : "v"(a), "v"(b));
  return r;
}

// ---------------- fused cast fp32 -> bf16 ----------------
__global__ void cast3_kernel(const float* __restrict__ a, int na4,
                             const float* __restrict__ b, int nb4,
                             const float* __restrict__ c, int nc4,
                             ushort* __restrict__ da, ushort* __restrict__ db,
                             ushort* __restrict__ dc) {
  int i = blockIdx.x * blockDim.x + threadIdx.x;
  const float* s; ushort* d; int off;
  if (i < na4) { s = a; d = da; off = i; }
  else if (i < na4 + nb4) { s = b; d = db; off = i - na4; }
  else if (i < na4 + nb4 + nc4) { s = c; d = dc; off = i - na4 - nb4; }
  else return;
  float4 f = ((const float4*)s)[off];
  ushort4 o;
  o.x = f2bf(f.x); o.y = f2bf(f.y); o.z = f2bf(f.z); o.w = f2bf(f.w);
  ((ushort4*)d)[off] = o;
}

// ---------------- GEMM v2: single-buffer, swizzled, stage-under-MFMA -------
// (r8-proven; Q epilogue scale 0.125*log2e; V written in PERMUTED-s layout
// matching attn's lane-local P fragments.)
template<int MODE, int BM, int BN>
__global__ __launch_bounds__(256, (BM == 64) ? 4 : 3)
void gemm_bt(const ushort* __restrict__ A, const ushort* __restrict__ B,
             ushort* __restrict__ q, ushort* __restrict__ k, ushort* __restrict__ vtp,
             float* __restrict__ outF, int M, int N, int K)
{
  constexpr int WN = BN / 64;
  constexpr int MI = (WN == 2) ? (BM / 32) : (BM / 64);
  constexpr int NI = 4;
  __shared__ ushort lA[BM * 64];
  __shared__ ushort lB[BN * 64];
  const int tid = threadIdx.x;
  const int w = tid >> 6, lane = tid & 63;
  const int m0 = blockIdx.x * BM, n0 = blockIdx.y * BN;
  const int g = lane >> 4, lr = lane & 15;
  const int wm = (WN == 2) ? (w >> 1) : w;
  const int wn = (WN == 2) ? (w & 1) : 0;

  const int r8 = lane >> 3;
  const int swz8 = ((lane & 7) ^ r8) * 8;
  const ushort* ga = A + (size_t)(m0 + w * 8 + r8) * K + swz8;
  const ushort* gb = B + (size_t)(n0 + w * 8 + r8) * K + swz8;
  const int xr = (lr & 7) << 3;

  v4f acc[MI][NI];
  const v4f zf = {0.0f, 0.0f, 0.0f, 0.0f};
#pragma unroll
  for (int mi = 0; mi < MI; mi++)
#pragma unroll
    for (int ni = 0; ni < NI; ni++) acc[mi][ni] = zf;

  auto stage = [&](int k0) {
#pragma unroll
    for (int i = 0; i < BM / 32; i++)
      __builtin_amdgcn_global_load_lds((const AS1 void*)(ga + (size_t)(i * 32) * K + k0),
                                       (AS3 void*)(&lA[(i * 32 + w * 8) * 64]), 16, 0, 0);
#pragma unroll
    for (int i = 0; i < BN / 32; i++)
      __builtin_amdgcn_global_load_lds((const AS1 void*)(gb + (size_t)(i * 32) * K + k0),
                                       (AS3 void*)(&lB[(i * 32 + w * 8) * 64]), 16, 0, 0);
  };

  stage(0);
  asm volatile("s_waitcnt vmcnt(0)" ::: "memory");
  asm volatile("s_barrier" ::: "memory");

  const int NTk = K >> 6;
  for (int t = 0; t < NTk; t++) {
    v8s af[MI][2], bf[NI][2];
#pragma unroll
    for (int mi = 0; mi < MI; mi++)
#pragma unroll
      for (int kc = 0; kc < 2; kc++)
        af[mi][kc] = *(const v8s*)(&lA[(wm * (MI * 16) + mi * 16 + lr) * 64 + ((kc * 32 + g * 8) ^ xr)]);
#pragma unroll
    for (int ni = 0; ni < NI; ni++)
#pragma unroll
      for (int kc = 0; kc < 2; kc++)
        bf[ni][kc] = *(const v8s*)(&lB[(wn * 64 + ni * 16 + lr) * 64 + ((kc * 32 + g * 8) ^ xr)]);
    asm volatile("s_waitcnt lgkmcnt(0)" ::: "memory");
    asm volatile("s_barrier" ::: "memory");
    if (t + 1 < NTk) stage((t + 1) * 64);
    __builtin_amdgcn_sched_barrier(0);
    __builtin_amdgcn_s_setprio(1);
#pragma unroll
    for (int kc = 0; kc < 2; kc++)
#pragma unroll
      for (int mi = 0; mi < MI; mi++)
#pragma unroll
        for (int ni = 0; ni < NI; ni++)
          acc[mi][ni] = __builtin_amdgcn_mfma_f32_16x16x32_bf16(af[mi][kc], bf[ni][kc], acc[mi][ni], 0, 0, 0);
    __builtin_amdgcn_s_setprio(0);
    asm volatile("s_waitcnt vmcnt(0)" ::: "memory");
    asm volatile("s_barrier" ::: "memory");
  }

#pragma unroll
  for (int mi = 0; mi < MI; mi++) {
#pragma unroll
    for (int ni = 0; ni < NI; ni++) {
      v4f c = acc[mi][ni];
      const int row0 = m0 + wm * (MI * 16) + mi * 16 + g * 4;
      const int col = n0 + wn * 64 + ni * 16 + lr;
      if (MODE == 0) {
        const int b = row0 >> 11, s0r = row0 & 2047;
        const int part = col >> 10, c2 = col & 1023;
        const int h = c2 >> 6, d = c2 & 63;
        if (part == 2) {
          // permuted-s position: p = (s&~31) | ((s>>2)&3)<<3 | ((s>>4)&1)<<2
          const int sp = (s0r & ~31) | (((s0r >> 2) & 3) << 3) | (((s0r >> 4) & 1) << 2);
          ushort4 pk4;
          pk4.x = f2bf(c[0]); pk4.y = f2bf(c[1]); pk4.z = f2bf(c[2]); pk4.w = f2bf(c[3]);
          *(ushort4*)(vtp + ((size_t)(b * 16 + h) * 64 + d) * 2048 + sp) = pk4;
        } else {
          const size_t idx = ((size_t)(b * 16 + h) * 2048 + s0r) * 64 + d;
#pragma unroll
          for (int r = 0; r < 4; r++) {
            const float val = c[r];
            if (part == 0) q[idx + (size_t)r * 64] = f2bf(val * 0.18033688f);
            else           k[idx + (size_t)r * 64] = f2bf(val);
          }
        }
      } else {
#pragma unroll
        for (int r = 0; r < 4; r++)
          outF[(size_t)(row0 + r) * N + col] = c[r];
      }
    }
  }
}

// ---------------- flash attention v9 (r14-proven): P fully in registers ----
// Swapped QK^T (mfma(K,Q) -> lane holds S[q=lr][k=ni*16+4g+r]); P packed via
// v_cvt_pk_bf16_f32 into lane-local A-frags under k-permutation pi; V stored
// globally in pi-layout so V frags are plain contiguous rdfrag reads. No P
// LDS, no shuffles in the loop. 4 blocks/CU (measured-best occupancy).
__global__ __launch_bounds__(256, 4)
void attn_kernel(const ushort* __restrict__ qh, const ushort* __restrict__ kh,
                 const ushort* __restrict__ vt, ushort* __restrict__ ao)
{
  __shared__ ushort lK0[64 * 64], lK1[64 * 64];
  __shared__ ushort lV0[64 * 64], lV1[64 * 64];

  const int bh = blockIdx.x;
  const int slot = blockIdx.y;
  const int chunk = (slot < 16) ? (31 - slot) : (slot - 16);
  const int q0 = chunk * 64;
  const int NT = chunk + 1;

  const int w = threadIdx.x >> 6;
  const int lane = threadIdx.x & 63;
  const int g = lane >> 4, lr = lane & 15;
  const int lsub = lane >> 3;
  const int swz8 = ((lane & 7) ^ lsub) * 8;
  const int wrow = q0 + w * 16;
  const int qq = wrow + lr;                 // this lane's q-row (swapped layout)

  const ushort* Qp = qh + (size_t)bh * 2048 * 64;
  const ushort* Kp = kh + (size_t)bh * 2048 * 64;
  const ushort* Vp = vt + (size_t)bh * 64 * 2048;

  v8s aq[2];
#pragma unroll
  for (int kc = 0; kc < 2; kc++)
    aq[kc] = *(const v8s*)(Qp + (size_t)(wrow + lr) * 64 + kc * 32 + g * 8);

  v4f o[4];
  float lp = 0.0f;                          // per-lane partial l for q=lr
  const v4f zf = {0.0f, 0.0f, 0.0f, 0.0f};
#pragma unroll
  for (int ni = 0; ni < 4; ni++) o[ni] = zf;

  auto stage = [&](ushort* dK, ushort* dV, int kv0) {
#pragma unroll
    for (int i = 0; i < 2; i++) {
      __builtin_amdgcn_global_load_lds(
          (const AS1 void*)(Kp + (size_t)(kv0 + i * 32 + w * 8 + lsub) * 64 + swz8),
          (AS3 void*)(dK + (i * 32 + w * 8) * 64), 16, 0, 0);
      __builtin_amdgcn_global_load_lds(
          (const AS1 void*)(Vp + (size_t)(i * 32 + w * 8 + lsub) * 2048 + kv0 + swz8),
          (AS3 void*)(dV + (i * 32 + w * 8) * 64), 16, 0, 0);
    }
  };

  auto rdfrag = [&](const ushort* base, int ni, int kc) -> v8s {
    const int row = ni * 16 + lr;
    const int off = (((kc * 64 + g * 16) ^ ((lr & 7) << 4)) >> 1);
    return *(const v8s*)(base + row * 64 + off);
  };

  auto compute = [&](const ushort* bK, const ushort* bV, int kv0, bool diag) {
    v4f s[4];
#pragma unroll
    for (int ni = 0; ni < 4; ni++) s[ni] = zf;
#pragma unroll
    for (int kc = 0; kc < 2; kc++) {
      v8s kf[4];
#pragma unroll
      for (int ni = 0; ni < 4; ni++) kf[ni] = rdfrag(bK, ni, kc);
      __builtin_amdgcn_s_setprio(1);
#pragma unroll
      for (int ni = 0; ni < 4; ni++)
        s[ni] = __builtin_amdgcn_mfma_f32_16x16x32_bf16(kf[ni], aq[kc], s[ni], 0, 0, 0);
      __builtin_amdgcn_s_setprio(0);
    }
    if (diag) {
#pragma unroll
      for (int ni = 0; ni < 4; ni++)
#pragma unroll
        for (int r = 0; r < 4; r++) {
          const int kk = kv0 + ni * 16 + g * 4 + r;
          if (kk > qq) s[ni][r] = -1.0e30f;
        }
    }
    // exp + pack: P fragment is lane-local under pi
    unsigned pk[8];
#pragma unroll
    for (int ni = 0; ni < 4; ni++) {
      const float p0 = exp2_hw(s[ni][0]);
      const float p1 = exp2_hw(s[ni][1]);
      const float p2 = exp2_hw(s[ni][2]);
      const float p3 = exp2_hw(s[ni][3]);
      lp += (p0 + p1) + (p2 + p3);
      pk[2 * ni]     = cvtpk_bf16(p0, p1);
      pk[2 * ni + 1] = cvtpk_bf16(p2, p3);
    }
#pragma unroll
    for (int kc = 0; kc < 2; kc++) {
      union { v8s v; unsigned u[4]; } ap;
      ap.u[0] = pk[4 * kc];     ap.u[1] = pk[4 * kc + 1];
      ap.u[2] = pk[4 * kc + 2]; ap.u[3] = pk[4 * kc + 3];
      v8s vf[4];
#pragma unroll
      for (int d = 0; d < 4; d++) vf[d] = rdfrag(bV, d, kc);
      __builtin_amdgcn_s_setprio(1);
#pragma unroll
      for (int d = 0; d < 4; d++)
        o[d] = __builtin_amdgcn_mfma_f32_16x16x32_bf16(ap.v, vf[d], o[d], 0, 0, 0);
      __builtin_amdgcn_s_setprio(0);
    }
  };

  stage(lK0, lV0, 0);
  asm volatile("s_waitcnt vmcnt(0)" ::: "memory");
  __builtin_amdgcn_s_barrier();

  for (int t = 0; t < NT; t++) {
    const int kv0 = t * 64;
    if ((t & 1) == 0) {
      if (t + 1 < NT) stage(lK1, lV1, kv0 + 64);
      compute(lK0, lV0, kv0, t == NT - 1);
    } else {
      if (t + 1 < NT) stage(lK0, lV0, kv0 + 64);
      compute(lK1, lV1, kv0, t == NT - 1);
    }
    asm volatile("s_waitcnt vmcnt(0)" ::: "memory");
    __builtin_amdgcn_s_barrier();
  }

  // finalize l[q=lr]: reduce across the 4 g-groups
  lp += __shfl_xor(lp, 16);
  lp += __shfl_xor(lp, 32);
  float rl[4];
#pragma unroll
  for (int r = 0; r < 4; r++)
    rl[r] = 1.0f / __shfl(lp, g * 4 + r);   // lane g*4+r holds l for q-row g*4+r

  const int b = bh >> 4, h = bh & 15;
#pragma unroll
  for (int ni = 0; ni < 4; ni++) {
#pragma unroll
    for (int r = 0; r < 4; r++) {
      const int srow = wrow + g * 4 + r;
      ao[((size_t)(b * 2048 + srow)) * 1024 + h * 64 + ni * 16 + lr] = f2bf(o[ni][r] * rl[r]);
    }
  }
}

extern "C" void kernel_launch(void* const* d_in, const int* in_sizes, int n_in,
                              void* d_out, int out_size, void* d_ws, size_t ws_size,
                              hipStream_t stream)
{
  const float* x     = (const float*)d_in[0];
  // d_in[1] = attention_mask (causal by construction; unused)
  const float* w_qkv = (const float*)d_in[2];
  const float* w_out = (const float*)d_in[3];
  float* out = (float*)d_out;

  char* ws = (char*)d_ws;
  ushort* xb  = (ushort*)(ws);                              // 8 MB (reused as ao)
  ushort* wqb = (ushort*)(ws + (size_t)8  * 1024 * 1024);   // 6 MB
  ushort* wob = (ushort*)(ws + (size_t)14 * 1024 * 1024);   // 2 MB
  ushort* qh  = (ushort*)(ws + (size_t)16 * 1024 * 1024);   // 8 MB
  ushort* kh  = (ushort*)(ws + (size_t)24 * 1024 * 1024);   // 8 MB
  ushort* vt  = (ushort*)(ws + (size_t)32 * 1024 * 1024);   // 8 MB
  ushort* ao  = xb;  // xb dead after gemm_qkv

  cast3_kernel<<<8192, 256, 0, stream>>>(x, 1048576, w_qkv, 786432, w_out, 262144,
                                         xb, wqb, wob);
  gemm_bt<0, 128, 128><<<dim3(32, 24), 256, 0, stream>>>(xb, wqb, qh, kh, vt, nullptr, 4096, 3072, 1024);
  attn_kernel<<<dim3(32, 32), 256, 0, stream>>>(qh, kh, vt, ao);
  gemm_bt<1, 64, 64><<<dim3(64, 16), 256, 0, stream>>>(ao, wob, nullptr, nullptr, nullptr, out, 4096, 1024, 1024);
}